// Round 20
// baseline (373.958 us; speedup 1.0000x reference)
//
#include <hip/hip_runtime.h>
#include <hip/hip_fp16.h>

#define NN 30000
#define ER 480000
#define ET 510000           // ER + NN self-loops
#define D 128
#define NH 8
#define HD 16
#define NL 7
#define SLOPE 0.2f
#define NB_SCAN 118         // ceil(NN/256)

typedef unsigned int uint32;
typedef unsigned short ushort;
typedef __attribute__((ext_vector_type(8))) short short8;
typedef __attribute__((ext_vector_type(4))) float f32x4;
typedef _Float16 h2_t __attribute__((ext_vector_type(2)));

#if defined(__has_builtin)
#if __has_builtin(__builtin_amdgcn_fdot2)
#define HAS_FDOT2 1
#endif
#endif

__device__ inline ushort f2bf(float f) {
    uint32 u = __float_as_uint(f);
    return (ushort)((u + 0x7fffu + ((u >> 16) & 1u)) >> 16);   // RNE
}
__device__ inline float bf2f(ushort h) {
    return __uint_as_float(((uint32)h) << 16);
}

// packed fp16 min/max (ROCm headers lack __hmin2/__hmax2; clang emits v_pk_*_f16)
__device__ inline __half2 hmax2p(__half2 a, __half2 b) {
    h2_t x = *reinterpret_cast<h2_t*>(&a), y = *reinterpret_cast<h2_t*>(&b);
    h2_t r;
    r[0] = x[0] > y[0] ? x[0] : y[0];
    r[1] = x[1] > y[1] ? x[1] : y[1];
    return *reinterpret_cast<__half2*>(&r);
}
__device__ inline __half2 hmin2p(__half2 a, __half2 b) {
    h2_t x = *reinterpret_cast<h2_t*>(&a), y = *reinterpret_cast<h2_t*>(&b);
    h2_t r;
    r[0] = x[0] < y[0] ? x[0] : y[0];
    r[1] = x[1] < y[1] ? x[1] : y[1];
    return *reinterpret_cast<__half2*>(&r);
}

__device__ inline float score_dot(__half2 l2, __half2 a2, float acc) {
#ifdef HAS_FDOT2
    h2_t x = *reinterpret_cast<h2_t*>(&l2);
    h2_t a = *reinterpret_cast<h2_t*>(&a2);
    return __builtin_amdgcn_fdot2(x, a, acc, false);
#else
    float2 lf = __half22float2(l2);
    float2 af = __half22float2(a2);
    return fmaf(lf.x, af.x, fmaf(lf.y, af.y, acc));
#endif
}

// ---------------- CSR build (dst is layer-invariant) ----------------

__global__ void k_hist(const int* __restrict__ ei, int* __restrict__ counts) {
    int i = blockIdx.x * 256 + threadIdx.x;
    if (i >= ET) return;
    int dst = (i < ER) ? ei[ER + i] : (i - ER);
    atomicAdd(&counts[dst], 1);
}

__global__ __launch_bounds__(256) void k_scan1(const int* __restrict__ counts,
                                               int* __restrict__ offsets,
                                               int* __restrict__ partials) {
    int t = threadIdx.x;
    int i = blockIdx.x * 256 + t;
    int v = (i < NN) ? counts[i] : 0;
    int lane = t & 63;
    int incl = v;
#pragma unroll
    for (int d = 1; d < 64; d <<= 1) {
        int u = __shfl_up(incl, d);
        if (lane >= d) incl += u;
    }
    __shared__ int ws[4];
    if (lane == 63) ws[t >> 6] = incl;
    __syncthreads();
    int wid = t >> 6;
    int base = 0;
    if (wid > 0) base += ws[0];
    if (wid > 1) base += ws[1];
    if (wid > 2) base += ws[2];
    if (i < NN) offsets[i] = base + incl - v;
    if (t == 255) partials[blockIdx.x] = base + incl;
}

__global__ __launch_bounds__(128) void k_scan2(int* __restrict__ partials,
                                               int* __restrict__ offsets) {
    int t = threadIdx.x;
    int v = (t < NB_SCAN) ? partials[t] : 0;
    int lane = t & 63;
    int incl = v;
#pragma unroll
    for (int d = 1; d < 64; d <<= 1) {
        int u = __shfl_up(incl, d);
        if (lane >= d) incl += u;
    }
    __shared__ int w0;
    if (t == 63) w0 = incl;
    __syncthreads();
    int base = (t >= 64) ? w0 : 0;
    if (t < NB_SCAN) partials[t] = base + incl - v;
    if (t == 127) offsets[NN] = base + incl;
}

__global__ void k_scan3(const int* __restrict__ partials, int* __restrict__ offsets,
                        int* __restrict__ cursor) {
    int i = blockIdx.x * 256 + threadIdx.x;
    if (i < NN) {
        int o = offsets[i] + partials[blockIdx.x];
        offsets[i] = o;
        cursor[i] = o;
    }
}

__global__ void k_scatter(const int* __restrict__ ei, int* __restrict__ cursor,
                          int* __restrict__ srcs) {
    int i = blockIdx.x * 256 + threadIdx.x;
    if (i >= ET) return;
    int src, dst;
    if (i < ER) { src = ei[i]; dst = ei[ER + i]; }
    else        { src = i - ER; dst = src; }
    int pos = atomicAdd(&cursor[dst], 1);
    srcs[pos] = src;
}

// sort each dst-segment ascending -> srcs is a pure function of the inputs
// (independent of atomic scatter order) -> deterministic across replays.
// One WAVE per node: in-register 64-lane bitonic sort (21 compare-exchanges).
// deg > 64 falls back to serial insertion (never hit for this graph: mean 17).
__global__ __launch_bounds__(256) void k_sortseg(const int* __restrict__ offsets,
                                                 int* __restrict__ srcs) {
    int n = (blockIdx.x * 256 + threadIdx.x) >> 6;   // wave id = node
    int lane = threadIdx.x & 63;
    if (n >= NN) return;
    int lo = offsets[n], hi = offsets[n + 1];
    int deg = hi - lo;
    if (deg <= 1) return;
    if (deg <= 64) {
        int v = (lane < deg) ? srcs[lo + lane] : 0x7fffffff;
#pragma unroll
        for (int k = 2; k <= 64; k <<= 1) {
#pragma unroll
            for (int j = k >> 1; j > 0; j >>= 1) {
                int u = __shfl_xor(v, j);
                bool up = ((lane & k) == 0);
                bool lower = ((lane & j) == 0);
                v = (lower == up) ? min(v, u) : max(v, u);
            }
        }
        if (lane < deg) srcs[lo + lane] = v;
    } else if (lane == 0) {
        for (int i = lo + 1; i < hi; ++i) {
            int v = srcs[i];
            int j = i - 1;
            while (j >= lo && srcs[j] > v) { srcs[j + 1] = srcs[j]; --j; }
            srcs[j + 1] = v;
        }
    }
}

// ---------------- W prep: transpose + bf16 hi/lo split, once for all layers ----------

__global__ __launch_bounds__(256) void k_wprep(const float* __restrict__ Wl,
                                               const float* __restrict__ Wr,
                                               ushort* __restrict__ Wth,
                                               ushort* __restrict__ Wtl) {
    int bx = blockIdx.x;              // NL*8 blocks
    int layer = bx >> 3;
    int n0 = (bx & 7) * 32;
    const float* WL = Wl + (size_t)layer * D * D;
    const float* WR = Wr + (size_t)layer * D * D;
    ushort* th = Wth + (size_t)layer * 256 * 128;
    ushort* tl = Wtl + (size_t)layer * 256 * 128;
    for (int idx = threadIdx.x; idx < 32 * 128; idx += 256) {
        int n = n0 + (idx >> 7);
        int k = idx & 127;
        float w = (n < 128) ? WL[k * 128 + n] : WR[k * 128 + (n - 128)];
        ushort h = f2bf(w);
        ushort e = f2bf(w - bf2f(h));
        th[n * 128 + k] = h;
        tl[n * 128 + k] = e;
    }
}

// ---------------- initial X split: fp32 -> bf16 hi/lo ----------------

__global__ void k_xsplit(const float* __restrict__ x,
                         ushort* __restrict__ xh, ushort* __restrict__ xe) {
    int i = (blockIdx.x * 256 + threadIdx.x) * 4;
    if (i >= NN * D) return;
    float4 f = *reinterpret_cast<const float4*>(x + i);
    ushort4 h, e;
    h.x = f2bf(f.x); e.x = f2bf(f.x - bf2f(h.x));
    h.y = f2bf(f.y); e.y = f2bf(f.y - bf2f(h.y));
    h.z = f2bf(f.z); e.z = f2bf(f.z - bf2f(h.z));
    h.w = f2bf(f.w); e.w = f2bf(f.w - bf2f(h.w));
    *reinterpret_cast<ushort4*>(xh + i) = h;
    *reinterpret_cast<ushort4*>(xe + i) = e;
}

// ---------------- MFMA split-bf16 GEMM: [xl | xr] = X @ [Wl | Wr] + [bl | br] -------
// grid (235, 4): TWO 64-row tiles per block share one W-chunk staging (halves the
// per-layer W re-read traffic: 60 -> 30 MB). A-frags in registers from global
// (coalesced); W chunk (hi+lo) in LDS. Epilogue bounces acc through an LDS tile so
// global stores are coalesced uint4. X@W ~= Xh@Wh + Xh@We + Xe@Wh.

__global__ __launch_bounds__(256) void k_mm(const ushort* __restrict__ Xh,
                                            const ushort* __restrict__ Xe,
                                            const ushort* __restrict__ Wth,
                                            const ushort* __restrict__ Wtl,
                                            const float* __restrict__ bl,
                                            const float* __restrict__ br,
                                            ushort* __restrict__ xlh,
                                            ushort* __restrict__ xrh) {
    __shared__ ushort Wh[64][136];
    __shared__ ushort We[64][136];
    __shared__ ushort Ld[64][72];      // 64 rows x 64 cols (+8 pad), fp16 out tile
    const int nq = blockIdx.y;         // col chunk [nq*64, nq*64+64) of 256
    const int tid = threadIdx.x;
    const int wv = tid >> 6;
    const int l  = tid & 63;
    const int lr = l & 15;             // A row / B col / C col
    const int kg = (l >> 4) * 8;       // k-group base within 32-chunk

    // stage W chunk (hi and lo) — once for both row tiles
    {
        int nn = tid >> 2;
        int ch = tid & 3;
        const ushort* wh = Wth + (size_t)(nq * 64 + nn) * 128;
        const ushort* wl = Wtl + (size_t)(nq * 64 + nn) * 128;
#pragma unroll
        for (int pass = 0; pass < 4; ++pass) {
            int ko = (ch * 4 + pass) * 8;
            *reinterpret_cast<uint4*>(&Wh[nn][ko]) = *reinterpret_cast<const uint4*>(wh + ko);
            *reinterpret_cast<uint4*>(&We[nn][ko]) = *reinterpret_cast<const uint4*>(wl + ko);
        }
    }
    __syncthreads();

#pragma unroll
    for (int rt = 0; rt < 2; ++rt) {
        const int row0 = blockIdx.x * 128 + rt * 64;
        // A-fragments in registers
        short8 Ah[4], Ae[4];
        {
            int row = row0 + wv * 16 + lr; if (row >= NN) row = NN - 1;
            const ushort* xh = Xh + (size_t)row * D;
            const ushort* xe = Xe + (size_t)row * D;
#pragma unroll
            for (int kc = 0; kc < 4; ++kc) {
                Ah[kc] = *reinterpret_cast<const short8*>(xh + kc * 32 + kg);
                Ae[kc] = *reinterpret_cast<const short8*>(xe + kc * 32 + kg);
            }
        }
        f32x4 acc[4] = {};
#pragma unroll
        for (int kc = 0; kc < 4; ++kc) {
#pragma unroll
            for (int nc = 0; nc < 4; ++nc) {
                short8 Bh = *reinterpret_cast<const short8*>(&Wh[nc * 16 + lr][kc * 32 + kg]);
                short8 Be = *reinterpret_cast<const short8*>(&We[nc * 16 + lr][kc * 32 + kg]);
                acc[nc] = __builtin_amdgcn_mfma_f32_16x16x32_bf16(Ah[kc], Bh, acc[nc], 0, 0, 0);
                acc[nc] = __builtin_amdgcn_mfma_f32_16x16x32_bf16(Ah[kc], Be, acc[nc], 0, 0, 0);
                acc[nc] = __builtin_amdgcn_mfma_f32_16x16x32_bf16(Ae[kc], Bh, acc[nc], 0, 0, 0);
            }
        }

        // epilogue 1: scatter into LDS (C/D layout col=lane&15, row=(lane>>4)*4+reg)
        const int lrow = wv * 16 + (l >> 4) * 4;
#pragma unroll
        for (int nc = 0; nc < 4; ++nc) {
            int g = nq * 64 + nc * 16 + lr;
            float bb = (g < 128) ? bl[g] : br[g - 128];
#pragma unroll
            for (int j = 0; j < 4; ++j)
                Ld[lrow + j][nc * 16 + lr] =
                    __half_as_ushort(__float2half_rn(acc[nc][j] + bb));
        }
        __syncthreads();

        // epilogue 2: coalesced stores — 4 threads per row cover 64 cols (128B)
        {
            int r = tid >> 2;                   // 0..63
            int c = (tid & 3) * 16;             // 0,16,32,48
            int row = row0 + r;
            if (row < NN) {
                ushort* dst = (nq < 2) ? (xlh + (size_t)row * D + nq * 64 + c)
                                       : (xrh + (size_t)row * D + (nq - 2) * 64 + c);
                uint4 v0 = *reinterpret_cast<const uint4*>(&Ld[r][c]);
                uint4 v1 = *reinterpret_cast<const uint4*>(&Ld[r][c + 8]);
                *reinterpret_cast<uint4*>(dst) = v0;
                *reinterpret_cast<uint4*>(dst + 8) = v1;
            }
        }
        __syncthreads();   // Ld safe to overwrite next rt (and W reads done)
    }
}

// ---------------- fused edge-score + softmax + aggregation ----------------
// One wave per destination node; 4 nodes per 256-thread block.
// QUARTER-WAVE SPLIT: each 16-lane quarter processes edge (base + q).
// Sub-lane sl owns dims {8sl..8sl+7} (one uint4 of fp16); head = sl>>1.
// Score reduce = single shfl_xor(1). Cross-quarter merge once at end.
// 8-edge main loop (R17-proven; 16-wide regressed: deg~17 -> tail-path bloat).
// No max subtraction (|e| <~ 5, exp safe in fp32). Value accum fp32.
// Output written as bf16 hi/lo split (next layer's pre-split X).

#define PROC(v, valid)                                                          \
    {                                                                           \
        __half2 vh0 = *reinterpret_cast<const __half2*>(&(v).x);                \
        __half2 vh1 = *reinterpret_cast<const __half2*>(&(v).y);                \
        __half2 vh2 = *reinterpret_cast<const __half2*>(&(v).z);                \
        __half2 vh3 = *reinterpret_cast<const __half2*>(&(v).w);                \
        __half2 t0 = __hadd2(vh0, rh0);                                         \
        __half2 t1 = __hadd2(vh1, rh1);                                         \
        __half2 t2 = __hadd2(vh2, rh2);                                         \
        __half2 t3 = __hadd2(vh3, rh3);                                         \
        __half2 l0 = __hfma2(hmin2p(t0, zero2), slope2, hmax2p(t0, zero2));     \
        __half2 l1 = __hfma2(hmin2p(t1, zero2), slope2, hmax2p(t1, zero2));     \
        __half2 l2 = __hfma2(hmin2p(t2, zero2), slope2, hmax2p(t2, zero2));     \
        __half2 l3 = __hfma2(hmin2p(t3, zero2), slope2, hmax2p(t3, zero2));     \
        float e = score_dot(l0, a0,                                             \
                  score_dot(l1, a1,                                             \
                  score_dot(l2, a2,                                             \
                  score_dot(l3, a3, 0.f))));                                    \
        e += __shfl_xor(e, 1);                                                  \
        float p = (valid) ? __expf(e) : 0.f;                                    \
        float2 f0 = __half22float2(vh0);                                        \
        float2 f1 = __half22float2(vh1);                                        \
        float2 f2 = __half22float2(vh2);                                        \
        float2 f3 = __half22float2(vh3);                                        \
        s += p;                                                                 \
        ac0 = fmaf(p, f0.x, ac0); ac1 = fmaf(p, f0.y, ac1);                     \
        ac2 = fmaf(p, f1.x, ac2); ac3 = fmaf(p, f1.y, ac3);                     \
        ac4 = fmaf(p, f2.x, ac4); ac5 = fmaf(p, f2.y, ac5);                     \
        ac6 = fmaf(p, f3.x, ac6); ac7 = fmaf(p, f3.y, ac7);                     \
    }

__global__ __launch_bounds__(256) void k_fused(const int* __restrict__ offsets,
                                               const int* __restrict__ srcs,
                                               const uint32* __restrict__ xlh,
                                               const uint32* __restrict__ xrh,
                                               const float* __restrict__ att,
                                               const float* __restrict__ bias,
                                               uint32* __restrict__ outH,
                                               uint32* __restrict__ outE) {
    const int tid = threadIdx.x;
    const int lane = tid & 63;
    const int q = lane >> 4;
    const int sl = lane & 15;
    const int n = blockIdx.x * 4 + (tid >> 6);
    const int off = offsets[n];
    const int deg = offsets[n + 1] - off;

    uint4 ru = *reinterpret_cast<const uint4*>(&xrh[(size_t)n * 64 + 4 * sl]);
    const __half2 rh0 = *reinterpret_cast<const __half2*>(&ru.x);
    const __half2 rh1 = *reinterpret_cast<const __half2*>(&ru.y);
    const __half2 rh2 = *reinterpret_cast<const __half2*>(&ru.z);
    const __half2 rh3 = *reinterpret_cast<const __half2*>(&ru.w);
    float4 af0 = *reinterpret_cast<const float4*>(&att[8 * sl]);
    float4 af1 = *reinterpret_cast<const float4*>(&att[8 * sl + 4]);
    const __half2 a0 = __floats2half2_rn(af0.x, af0.y);
    const __half2 a1 = __floats2half2_rn(af0.z, af0.w);
    const __half2 a2 = __floats2half2_rn(af1.x, af1.y);
    const __half2 a3 = __floats2half2_rn(af1.z, af1.w);
    const __half2 zero2 = __float2half2_rn(0.f);
    const __half2 slope2 = __float2half2_rn(SLOPE);

    float s = 0.f;
    float ac0 = 0.f, ac1 = 0.f, ac2 = 0.f, ac3 = 0.f;
    float ac4 = 0.f, ac5 = 0.f, ac6 = 0.f, ac7 = 0.f;

    int base = 0;
    for (; base + 8 <= deg; base += 8) {
        int s0 = srcs[off + base + q];
        int s1 = srcs[off + base + 4 + q];
        uint4 v0 = *reinterpret_cast<const uint4*>(&xlh[(size_t)s0 * 64 + 4 * sl]);
        uint4 v1 = *reinterpret_cast<const uint4*>(&xlh[(size_t)s1 * 64 + 4 * sl]);
        PROC(v0, true);
        PROC(v1, true);
    }
    for (; base < deg; base += 4) {
        int idx = base + q;
        bool valid = idx < deg;
        int sid = srcs[off + (valid ? idx : deg - 1)];
        uint4 v = *reinterpret_cast<const uint4*>(&xlh[(size_t)sid * 64 + 4 * sl]);
        PROC(v, valid);
    }

    // merge quarters
    s += __shfl_xor(s, 16);  s += __shfl_xor(s, 32);
    ac0 += __shfl_xor(ac0, 16); ac0 += __shfl_xor(ac0, 32);
    ac1 += __shfl_xor(ac1, 16); ac1 += __shfl_xor(ac1, 32);
    ac2 += __shfl_xor(ac2, 16); ac2 += __shfl_xor(ac2, 32);
    ac3 += __shfl_xor(ac3, 16); ac3 += __shfl_xor(ac3, 32);
    ac4 += __shfl_xor(ac4, 16); ac4 += __shfl_xor(ac4, 32);
    ac5 += __shfl_xor(ac5, 16); ac5 += __shfl_xor(ac5, 32);
    ac6 += __shfl_xor(ac6, 16); ac6 += __shfl_xor(ac6, 32);
    ac7 += __shfl_xor(ac7, 16); ac7 += __shfl_xor(ac7, 32);

    if (q == 0) {
        float inv = 1.f / (s + 1e-16f);
        float4 b0 = *reinterpret_cast<const float4*>(&bias[8 * sl]);
        float4 b1 = *reinterpret_cast<const float4*>(&bias[8 * sl + 4]);
        float o0 = ac0 * inv + b0.x, o1 = ac1 * inv + b0.y;
        float o2 = ac2 * inv + b0.z, o3 = ac3 * inv + b0.w;
        float o4 = ac4 * inv + b1.x, o5 = ac5 * inv + b1.y;
        float o6 = ac6 * inv + b1.z, o7 = ac7 * inv + b1.w;
        ushort h0 = f2bf(o0), h1 = f2bf(o1), h2 = f2bf(o2), h3 = f2bf(o3);
        ushort h4 = f2bf(o4), h5 = f2bf(o5), h6 = f2bf(o6), h7 = f2bf(o7);
        uint4 wh, we;
        wh.x = (uint32)h0 | ((uint32)h1 << 16);
        wh.y = (uint32)h2 | ((uint32)h3 << 16);
        wh.z = (uint32)h4 | ((uint32)h5 << 16);
        wh.w = (uint32)h6 | ((uint32)h7 << 16);
        we.x = (uint32)f2bf(o0 - bf2f(h0)) | ((uint32)f2bf(o1 - bf2f(h1)) << 16);
        we.y = (uint32)f2bf(o2 - bf2f(h2)) | ((uint32)f2bf(o3 - bf2f(h3)) << 16);
        we.z = (uint32)f2bf(o4 - bf2f(h4)) | ((uint32)f2bf(o5 - bf2f(h5)) << 16);
        we.w = (uint32)f2bf(o6 - bf2f(h6)) | ((uint32)f2bf(o7 - bf2f(h7)) << 16);
        *reinterpret_cast<uint4*>(&outH[(size_t)n * 64 + 4 * sl]) = wh;
        *reinterpret_cast<uint4*>(&outE[(size_t)n * 64 + 4 * sl]) = we;
    }
}

// ---------------- output head (reads split x) ----------------

__global__ void k_out(const ushort* __restrict__ xh, const ushort* __restrict__ xe,
                      const float* __restrict__ Wout, const float* __restrict__ bout,
                      float* __restrict__ y) {
    int lane = threadIdx.x;
#pragma unroll
    for (int i = 0; i < 2; ++i) {
        float x0 = bf2f(xh[i * D + lane]) + bf2f(xe[i * D + lane]);
        float x1 = bf2f(xh[i * D + 64 + lane]) + bf2f(xe[i * D + 64 + lane]);
        float v = x0 * Wout[lane] + x1 * Wout[64 + lane];
        v += __shfl_xor(v, 1); v += __shfl_xor(v, 2); v += __shfl_xor(v, 4);
        v += __shfl_xor(v, 8); v += __shfl_xor(v, 16); v += __shfl_xor(v, 32);
        if (lane == 0) y[i] = v + bout[0];
    }
}

// ---------------- launch ----------------

extern "C" void kernel_launch(void* const* d_in, const int* in_sizes, int n_in,
                              void* d_out, int out_size, void* d_ws, size_t ws_size,
                              hipStream_t stream) {
    const float* x_in = (const float*)d_in[0];
    const int*   ei   = (const int*)d_in[1];
    const float* Wl   = (const float*)d_in[2];
    const float* bl   = (const float*)d_in[3];
    const float* Wr   = (const float*)d_in[4];
    const float* br   = (const float*)d_in[5];
    const float* att  = (const float*)d_in[6];
    const float* bias = (const float*)d_in[7];
    const float* Wout = (const float*)d_in[8];
    const float* bout = (const float*)d_in[9];
    float* y = (float*)d_out;

    char* ws = (char*)d_ws;
    size_t o = 0;
    auto alloc = [&](size_t bytes) -> void* {
        void* p = ws + o;
        o = (o + bytes + 255) & ~(size_t)255;
        return p;
    };
    ushort* XhA = (ushort*)alloc((size_t)NN * D * 2);
    ushort* XeA = (ushort*)alloc((size_t)NN * D * 2);
    ushort* XhB = (ushort*)alloc((size_t)NN * D * 2);
    ushort* XeB = (ushort*)alloc((size_t)NN * D * 2);
    ushort* xlh = (ushort*)alloc((size_t)NN * D * 2);
    ushort* xrh = (ushort*)alloc((size_t)NN * D * 2);
    ushort* Wth = (ushort*)alloc((size_t)NL * 256 * 128 * 2);
    ushort* Wtl = (ushort*)alloc((size_t)NL * 256 * 128 * 2);
    int* counts   = (int*)alloc((size_t)NN * 4);
    int* offsets  = (int*)alloc(((size_t)NN + 1) * 4);
    int* cursor   = (int*)alloc((size_t)NN * 4);
    int* srcs     = (int*)alloc((size_t)ET * 4);
    int* partials = (int*)alloc(256 * 4);
    (void)ws_size; (void)in_sizes; (void)n_in; (void)out_size;

    // CSR by dst with resolved srcs (layer-invariant) + deterministic segment
    // sort (wave bitonic) + W prep + X split
    hipMemsetAsync(counts, 0, (size_t)NN * 4, stream);
    k_hist<<<(ET + 255) / 256, 256, 0, stream>>>(ei, counts);
    k_scan1<<<NB_SCAN, 256, 0, stream>>>(counts, offsets, partials);
    k_scan2<<<1, 128, 0, stream>>>(partials, offsets);
    k_scan3<<<NB_SCAN, 256, 0, stream>>>(partials, offsets, cursor);
    k_scatter<<<(ET + 255) / 256, 256, 0, stream>>>(ei, cursor, srcs);
    k_sortseg<<<(NN + 3) / 4, 256, 0, stream>>>(offsets, srcs);
    k_wprep<<<NL * 8, 256, 0, stream>>>(Wl, Wr, Wth, Wtl);
    k_xsplit<<<NN * D / 1024, 256, 0, stream>>>(x_in, XhA, XeA);

    const int mgrid = (NN + 127) / 128;   // 235 (two 64-row tiles per block)
    for (int i = 0; i < NL; ++i) {
        const ushort* inH = (i & 1) ? XhB : XhA;
        const ushort* inE = (i & 1) ? XeB : XeA;
        ushort* oH = (i & 1) ? XhA : XhB;
        ushort* oE = (i & 1) ? XeA : XeB;
        k_mm<<<dim3(mgrid, 4), 256, 0, stream>>>(inH, inE,
                                                 Wth + (size_t)i * 256 * 128,
                                                 Wtl + (size_t)i * 256 * 128,
                                                 bl + i * D, br + i * D, xlh, xrh);
        k_fused<<<NN / 4, 256, 0, stream>>>(offsets, srcs, (const uint32*)xlh,
                                            (const uint32*)xrh,
                                            att + i * NH * HD, bias + i * D,
                                            (uint32*)oH, (uint32*)oE);
    }
    k_out<<<1, 64, 0, stream>>>(XhB, XeB, Wout, bout, y);  // i=6 even -> out B
}

// Round 21
// 365.484 us; speedup vs baseline: 1.0232x; 1.0232x over previous
//
#include <hip/hip_runtime.h>
#include <hip/hip_fp16.h>

#define NN 30000
#define ER 480000
#define ET 510000           // ER + NN self-loops
#define D 128
#define NH 8
#define HD 16
#define NL 7
#define SLOPE 0.2f
#define NB_SCAN 118         // ceil(NN/256)

typedef unsigned int uint32;
typedef unsigned short ushort;
typedef __attribute__((ext_vector_type(8))) short short8;
typedef __attribute__((ext_vector_type(4))) float f32x4;
typedef _Float16 h2_t __attribute__((ext_vector_type(2)));

#if defined(__has_builtin)
#if __has_builtin(__builtin_amdgcn_fdot2)
#define HAS_FDOT2 1
#endif
#endif

__device__ inline ushort f2bf(float f) {
    uint32 u = __float_as_uint(f);
    return (ushort)((u + 0x7fffu + ((u >> 16) & 1u)) >> 16);   // RNE
}
__device__ inline float bf2f(ushort h) {
    return __uint_as_float(((uint32)h) << 16);
}

// packed fp16 min/max (ROCm headers lack __hmin2/__hmax2; clang emits v_pk_*_f16)
__device__ inline __half2 hmax2p(__half2 a, __half2 b) {
    h2_t x = *reinterpret_cast<h2_t*>(&a), y = *reinterpret_cast<h2_t*>(&b);
    h2_t r;
    r[0] = x[0] > y[0] ? x[0] : y[0];
    r[1] = x[1] > y[1] ? x[1] : y[1];
    return *reinterpret_cast<__half2*>(&r);
}
__device__ inline __half2 hmin2p(__half2 a, __half2 b) {
    h2_t x = *reinterpret_cast<h2_t*>(&a), y = *reinterpret_cast<h2_t*>(&b);
    h2_t r;
    r[0] = x[0] < y[0] ? x[0] : y[0];
    r[1] = x[1] < y[1] ? x[1] : y[1];
    return *reinterpret_cast<__half2*>(&r);
}

__device__ inline float score_dot(__half2 l2, __half2 a2, float acc) {
#ifdef HAS_FDOT2
    h2_t x = *reinterpret_cast<h2_t*>(&l2);
    h2_t a = *reinterpret_cast<h2_t*>(&a2);
    return __builtin_amdgcn_fdot2(x, a, acc, false);
#else
    float2 lf = __half22float2(l2);
    float2 af = __half22float2(a2);
    return fmaf(lf.x, af.x, fmaf(lf.y, af.y, acc));
#endif
}

// ---------------- CSR build (dst is layer-invariant) ----------------

__global__ void k_hist(const int* __restrict__ ei, int* __restrict__ counts) {
    int i = blockIdx.x * 256 + threadIdx.x;
    if (i >= ET) return;
    int dst = (i < ER) ? ei[ER + i] : (i - ER);
    atomicAdd(&counts[dst], 1);
}

__global__ __launch_bounds__(256) void k_scan1(const int* __restrict__ counts,
                                               int* __restrict__ offsets,
                                               int* __restrict__ partials) {
    int t = threadIdx.x;
    int i = blockIdx.x * 256 + t;
    int v = (i < NN) ? counts[i] : 0;
    int lane = t & 63;
    int incl = v;
#pragma unroll
    for (int d = 1; d < 64; d <<= 1) {
        int u = __shfl_up(incl, d);
        if (lane >= d) incl += u;
    }
    __shared__ int ws[4];
    if (lane == 63) ws[t >> 6] = incl;
    __syncthreads();
    int wid = t >> 6;
    int base = 0;
    if (wid > 0) base += ws[0];
    if (wid > 1) base += ws[1];
    if (wid > 2) base += ws[2];
    if (i < NN) offsets[i] = base + incl - v;
    if (t == 255) partials[blockIdx.x] = base + incl;
}

__global__ __launch_bounds__(128) void k_scan2(int* __restrict__ partials,
                                               int* __restrict__ offsets) {
    int t = threadIdx.x;
    int v = (t < NB_SCAN) ? partials[t] : 0;
    int lane = t & 63;
    int incl = v;
#pragma unroll
    for (int d = 1; d < 64; d <<= 1) {
        int u = __shfl_up(incl, d);
        if (lane >= d) incl += u;
    }
    __shared__ int w0;
    if (t == 63) w0 = incl;
    __syncthreads();
    int base = (t >= 64) ? w0 : 0;
    if (t < NB_SCAN) partials[t] = base + incl - v;
    if (t == 127) offsets[NN] = base + incl;
}

__global__ void k_scan3(const int* __restrict__ partials, int* __restrict__ offsets,
                        int* __restrict__ cursor) {
    int i = blockIdx.x * 256 + threadIdx.x;
    if (i < NN) {
        int o = offsets[i] + partials[blockIdx.x];
        offsets[i] = o;
        cursor[i] = o;
    }
}

__global__ void k_scatter(const int* __restrict__ ei, int* __restrict__ cursor,
                          int* __restrict__ srcs) {
    int i = blockIdx.x * 256 + threadIdx.x;
    if (i >= ET) return;
    int src, dst;
    if (i < ER) { src = ei[i]; dst = ei[ER + i]; }
    else        { src = i - ER; dst = src; }
    int pos = atomicAdd(&cursor[dst], 1);
    srcs[pos] = src;
}

// sort each dst-segment ascending -> srcs is a pure function of the inputs
// (independent of atomic scatter order) -> deterministic across replays.
// One WAVE per node: in-register 64-lane bitonic sort (21 compare-exchanges).
// deg > 64 falls back to serial insertion (never hit for this graph: mean 17).
__global__ __launch_bounds__(256) void k_sortseg(const int* __restrict__ offsets,
                                                 int* __restrict__ srcs) {
    int n = (blockIdx.x * 256 + threadIdx.x) >> 6;   // wave id = node
    int lane = threadIdx.x & 63;
    if (n >= NN) return;
    int lo = offsets[n], hi = offsets[n + 1];
    int deg = hi - lo;
    if (deg <= 1) return;
    if (deg <= 64) {
        int v = (lane < deg) ? srcs[lo + lane] : 0x7fffffff;
#pragma unroll
        for (int k = 2; k <= 64; k <<= 1) {
#pragma unroll
            for (int j = k >> 1; j > 0; j >>= 1) {
                int u = __shfl_xor(v, j);
                bool up = ((lane & k) == 0);
                bool lower = ((lane & j) == 0);
                v = (lower == up) ? min(v, u) : max(v, u);
            }
        }
        if (lane < deg) srcs[lo + lane] = v;
    } else if (lane == 0) {
        for (int i = lo + 1; i < hi; ++i) {
            int v = srcs[i];
            int j = i - 1;
            while (j >= lo && srcs[j] > v) { srcs[j + 1] = srcs[j]; --j; }
            srcs[j + 1] = v;
        }
    }
}

// ---------------- W prep: transpose + bf16 hi/lo split, once for all layers ----------

__global__ __launch_bounds__(256) void k_wprep(const float* __restrict__ Wl,
                                               const float* __restrict__ Wr,
                                               ushort* __restrict__ Wth,
                                               ushort* __restrict__ Wtl) {
    int bx = blockIdx.x;              // NL*8 blocks
    int layer = bx >> 3;
    int n0 = (bx & 7) * 32;
    const float* WL = Wl + (size_t)layer * D * D;
    const float* WR = Wr + (size_t)layer * D * D;
    ushort* th = Wth + (size_t)layer * 256 * 128;
    ushort* tl = Wtl + (size_t)layer * 256 * 128;
    for (int idx = threadIdx.x; idx < 32 * 128; idx += 256) {
        int n = n0 + (idx >> 7);
        int k = idx & 127;
        float w = (n < 128) ? WL[k * 128 + n] : WR[k * 128 + (n - 128)];
        ushort h = f2bf(w);
        ushort e = f2bf(w - bf2f(h));
        th[n * 128 + k] = h;
        tl[n * 128 + k] = e;
    }
}

// ---------------- initial X split: fp32 -> bf16 hi/lo ----------------

__global__ void k_xsplit(const float* __restrict__ x,
                         ushort* __restrict__ xh, ushort* __restrict__ xe) {
    int i = (blockIdx.x * 256 + threadIdx.x) * 4;
    if (i >= NN * D) return;
    float4 f = *reinterpret_cast<const float4*>(x + i);
    ushort4 h, e;
    h.x = f2bf(f.x); e.x = f2bf(f.x - bf2f(h.x));
    h.y = f2bf(f.y); e.y = f2bf(f.y - bf2f(h.y));
    h.z = f2bf(f.z); e.z = f2bf(f.z - bf2f(h.z));
    h.w = f2bf(f.w); e.w = f2bf(f.w - bf2f(h.w));
    *reinterpret_cast<ushort4*>(xh + i) = h;
    *reinterpret_cast<ushort4*>(xe + i) = e;
}

// ---------------- MFMA split-bf16 GEMM: [xl | xr] = X @ [Wl | Wr] + [bl | br] -------
// grid (469, 4): 64-row x 64-col chunk -> 1876 blocks. A-frags in registers from
// global (coalesced); W chunk (hi+lo) in LDS. Epilogue bounces acc through an LDS
// tile so global stores are coalesced uint4. X@W ~= Xh@Wh + Xh@We + Xe@Wh.

__global__ __launch_bounds__(256) void k_mm(const ushort* __restrict__ Xh,
                                            const ushort* __restrict__ Xe,
                                            const ushort* __restrict__ Wth,
                                            const ushort* __restrict__ Wtl,
                                            const float* __restrict__ bl,
                                            const float* __restrict__ br,
                                            ushort* __restrict__ xlh,
                                            ushort* __restrict__ xrh) {
    __shared__ ushort Wh[64][136];
    __shared__ ushort We[64][136];
    __shared__ ushort Ld[64][72];      // 64 rows x 64 cols (+8 pad), fp16 out tile
    const int row0 = blockIdx.x * 64;
    const int nq = blockIdx.y;         // col chunk [nq*64, nq*64+64) of 256
    const int tid = threadIdx.x;
    const int wv = tid >> 6;
    const int l  = tid & 63;
    const int lr = l & 15;             // A row / B col / C col
    const int kg = (l >> 4) * 8;       // k-group base within 32-chunk

    // stage W chunk (hi and lo)
    {
        int nn = tid >> 2;
        int ch = tid & 3;
        const ushort* wh = Wth + (size_t)(nq * 64 + nn) * 128;
        const ushort* wl = Wtl + (size_t)(nq * 64 + nn) * 128;
#pragma unroll
        for (int pass = 0; pass < 4; ++pass) {
            int ko = (ch * 4 + pass) * 8;
            *reinterpret_cast<uint4*>(&Wh[nn][ko]) = *reinterpret_cast<const uint4*>(wh + ko);
            *reinterpret_cast<uint4*>(&We[nn][ko]) = *reinterpret_cast<const uint4*>(wl + ko);
        }
    }
    // A-fragments in registers
    short8 Ah[4], Ae[4];
    {
        int row = row0 + wv * 16 + lr; if (row >= NN) row = NN - 1;
        const ushort* xh = Xh + (size_t)row * D;
        const ushort* xe = Xe + (size_t)row * D;
#pragma unroll
        for (int kc = 0; kc < 4; ++kc) {
            Ah[kc] = *reinterpret_cast<const short8*>(xh + kc * 32 + kg);
            Ae[kc] = *reinterpret_cast<const short8*>(xe + kc * 32 + kg);
        }
    }
    __syncthreads();

    f32x4 acc[4] = {};
#pragma unroll
    for (int kc = 0; kc < 4; ++kc) {
#pragma unroll
        for (int nc = 0; nc < 4; ++nc) {
            short8 Bh = *reinterpret_cast<const short8*>(&Wh[nc * 16 + lr][kc * 32 + kg]);
            short8 Be = *reinterpret_cast<const short8*>(&We[nc * 16 + lr][kc * 32 + kg]);
            acc[nc] = __builtin_amdgcn_mfma_f32_16x16x32_bf16(Ah[kc], Bh, acc[nc], 0, 0, 0);
            acc[nc] = __builtin_amdgcn_mfma_f32_16x16x32_bf16(Ah[kc], Be, acc[nc], 0, 0, 0);
            acc[nc] = __builtin_amdgcn_mfma_f32_16x16x32_bf16(Ae[kc], Bh, acc[nc], 0, 0, 0);
        }
    }

    // epilogue 1: scatter into LDS (C/D layout col=lane&15, row=(lane>>4)*4+reg)
    const int lrow = wv * 16 + (l >> 4) * 4;   // local row base
#pragma unroll
    for (int nc = 0; nc < 4; ++nc) {
        int g = nq * 64 + nc * 16 + lr;
        float bb = (g < 128) ? bl[g] : br[g - 128];
#pragma unroll
        for (int j = 0; j < 4; ++j)
            Ld[lrow + j][nc * 16 + lr] =
                __half_as_ushort(__float2half_rn(acc[nc][j] + bb));
    }
    __syncthreads();

    // epilogue 2: coalesced stores — 4 threads per row cover 64 cols (128B)
    {
        int r = tid >> 2;                   // 0..63
        int c = (tid & 3) * 16;             // 0,16,32,48
        int row = row0 + r;
        if (row < NN) {
            ushort* dst = (nq < 2) ? (xlh + (size_t)row * D + nq * 64 + c)
                                   : (xrh + (size_t)row * D + (nq - 2) * 64 + c);
            uint4 v0 = *reinterpret_cast<const uint4*>(&Ld[r][c]);
            uint4 v1 = *reinterpret_cast<const uint4*>(&Ld[r][c + 8]);
            *reinterpret_cast<uint4*>(dst) = v0;
            *reinterpret_cast<uint4*>(dst + 8) = v1;
        }
    }
}

// ---------------- fused edge-score + softmax + aggregation ----------------
// One wave per destination node; 4 nodes per 256-thread block.
// QUARTER-WAVE SPLIT: each 16-lane quarter processes edge (base + q).
// Sub-lane sl owns dims {8sl..8sl+7} (one uint4 of fp16); head = sl>>1.
// Score reduce = single shfl_xor(1). Cross-quarter merge once at end.
// 8-edge main loop (R17-proven; 16-wide regressed: deg~17 -> tail-path bloat).
// No max subtraction (|e| <~ 5, exp safe in fp32). Value accum fp32.
// Output written as bf16 hi/lo split (next layer's pre-split X).

#define PROC(v, valid)                                                          \
    {                                                                           \
        __half2 vh0 = *reinterpret_cast<const __half2*>(&(v).x);                \
        __half2 vh1 = *reinterpret_cast<const __half2*>(&(v).y);                \
        __half2 vh2 = *reinterpret_cast<const __half2*>(&(v).z);                \
        __half2 vh3 = *reinterpret_cast<const __half2*>(&(v).w);                \
        __half2 t0 = __hadd2(vh0, rh0);                                         \
        __half2 t1 = __hadd2(vh1, rh1);                                         \
        __half2 t2 = __hadd2(vh2, rh2);                                         \
        __half2 t3 = __hadd2(vh3, rh3);                                         \
        __half2 l0 = __hfma2(hmin2p(t0, zero2), slope2, hmax2p(t0, zero2));     \
        __half2 l1 = __hfma2(hmin2p(t1, zero2), slope2, hmax2p(t1, zero2));     \
        __half2 l2 = __hfma2(hmin2p(t2, zero2), slope2, hmax2p(t2, zero2));     \
        __half2 l3 = __hfma2(hmin2p(t3, zero2), slope2, hmax2p(t3, zero2));     \
        float e = score_dot(l0, a0,                                             \
                  score_dot(l1, a1,                                             \
                  score_dot(l2, a2,                                             \
                  score_dot(l3, a3, 0.f))));                                    \
        e += __shfl_xor(e, 1);                                                  \
        float p = (valid) ? __expf(e) : 0.f;                                    \
        float2 f0 = __half22float2(vh0);                                        \
        float2 f1 = __half22float2(vh1);                                        \
        float2 f2 = __half22float2(vh2);                                        \
        float2 f3 = __half22float2(vh3);                                        \
        s += p;                                                                 \
        ac0 = fmaf(p, f0.x, ac0); ac1 = fmaf(p, f0.y, ac1);                     \
        ac2 = fmaf(p, f1.x, ac2); ac3 = fmaf(p, f1.y, ac3);                     \
        ac4 = fmaf(p, f2.x, ac4); ac5 = fmaf(p, f2.y, ac5);                     \
        ac6 = fmaf(p, f3.x, ac6); ac7 = fmaf(p, f3.y, ac7);                     \
    }

__global__ __launch_bounds__(256) void k_fused(const int* __restrict__ offsets,
                                               const int* __restrict__ srcs,
                                               const uint32* __restrict__ xlh,
                                               const uint32* __restrict__ xrh,
                                               const float* __restrict__ att,
                                               const float* __restrict__ bias,
                                               uint32* __restrict__ outH,
                                               uint32* __restrict__ outE) {
    const int tid = threadIdx.x;
    const int lane = tid & 63;
    const int q = lane >> 4;
    const int sl = lane & 15;
    const int n = blockIdx.x * 4 + (tid >> 6);
    const int off = offsets[n];
    const int deg = offsets[n + 1] - off;

    uint4 ru = *reinterpret_cast<const uint4*>(&xrh[(size_t)n * 64 + 4 * sl]);
    const __half2 rh0 = *reinterpret_cast<const __half2*>(&ru.x);
    const __half2 rh1 = *reinterpret_cast<const __half2*>(&ru.y);
    const __half2 rh2 = *reinterpret_cast<const __half2*>(&ru.z);
    const __half2 rh3 = *reinterpret_cast<const __half2*>(&ru.w);
    float4 af0 = *reinterpret_cast<const float4*>(&att[8 * sl]);
    float4 af1 = *reinterpret_cast<const float4*>(&att[8 * sl + 4]);
    const __half2 a0 = __floats2half2_rn(af0.x, af0.y);
    const __half2 a1 = __floats2half2_rn(af0.z, af0.w);
    const __half2 a2 = __floats2half2_rn(af1.x, af1.y);
    const __half2 a3 = __floats2half2_rn(af1.z, af1.w);
    const __half2 zero2 = __float2half2_rn(0.f);
    const __half2 slope2 = __float2half2_rn(SLOPE);

    float s = 0.f;
    float ac0 = 0.f, ac1 = 0.f, ac2 = 0.f, ac3 = 0.f;
    float ac4 = 0.f, ac5 = 0.f, ac6 = 0.f, ac7 = 0.f;

    int base = 0;
    for (; base + 8 <= deg; base += 8) {
        int s0 = srcs[off + base + q];
        int s1 = srcs[off + base + 4 + q];
        uint4 v0 = *reinterpret_cast<const uint4*>(&xlh[(size_t)s0 * 64 + 4 * sl]);
        uint4 v1 = *reinterpret_cast<const uint4*>(&xlh[(size_t)s1 * 64 + 4 * sl]);
        PROC(v0, true);
        PROC(v1, true);
    }
    for (; base < deg; base += 4) {
        int idx = base + q;
        bool valid = idx < deg;
        int sid = srcs[off + (valid ? idx : deg - 1)];
        uint4 v = *reinterpret_cast<const uint4*>(&xlh[(size_t)sid * 64 + 4 * sl]);
        PROC(v, valid);
    }

    // merge quarters
    s += __shfl_xor(s, 16);  s += __shfl_xor(s, 32);
    ac0 += __shfl_xor(ac0, 16); ac0 += __shfl_xor(ac0, 32);
    ac1 += __shfl_xor(ac1, 16); ac1 += __shfl_xor(ac1, 32);
    ac2 += __shfl_xor(ac2, 16); ac2 += __shfl_xor(ac2, 32);
    ac3 += __shfl_xor(ac3, 16); ac3 += __shfl_xor(ac3, 32);
    ac4 += __shfl_xor(ac4, 16); ac4 += __shfl_xor(ac4, 32);
    ac5 += __shfl_xor(ac5, 16); ac5 += __shfl_xor(ac5, 32);
    ac6 += __shfl_xor(ac6, 16); ac6 += __shfl_xor(ac6, 32);
    ac7 += __shfl_xor(ac7, 16); ac7 += __shfl_xor(ac7, 32);

    if (q == 0) {
        float inv = 1.f / (s + 1e-16f);
        float4 b0 = *reinterpret_cast<const float4*>(&bias[8 * sl]);
        float4 b1 = *reinterpret_cast<const float4*>(&bias[8 * sl + 4]);
        float o0 = ac0 * inv + b0.x, o1 = ac1 * inv + b0.y;
        float o2 = ac2 * inv + b0.z, o3 = ac3 * inv + b0.w;
        float o4 = ac4 * inv + b1.x, o5 = ac5 * inv + b1.y;
        float o6 = ac6 * inv + b1.z, o7 = ac7 * inv + b1.w;
        ushort h0 = f2bf(o0), h1 = f2bf(o1), h2 = f2bf(o2), h3 = f2bf(o3);
        ushort h4 = f2bf(o4), h5 = f2bf(o5), h6 = f2bf(o6), h7 = f2bf(o7);
        uint4 wh, we;
        wh.x = (uint32)h0 | ((uint32)h1 << 16);
        wh.y = (uint32)h2 | ((uint32)h3 << 16);
        wh.z = (uint32)h4 | ((uint32)h5 << 16);
        wh.w = (uint32)h6 | ((uint32)h7 << 16);
        we.x = (uint32)f2bf(o0 - bf2f(h0)) | ((uint32)f2bf(o1 - bf2f(h1)) << 16);
        we.y = (uint32)f2bf(o2 - bf2f(h2)) | ((uint32)f2bf(o3 - bf2f(h3)) << 16);
        we.z = (uint32)f2bf(o4 - bf2f(h4)) | ((uint32)f2bf(o5 - bf2f(h5)) << 16);
        we.w = (uint32)f2bf(o6 - bf2f(h6)) | ((uint32)f2bf(o7 - bf2f(h7)) << 16);
        *reinterpret_cast<uint4*>(&outH[(size_t)n * 64 + 4 * sl]) = wh;
        *reinterpret_cast<uint4*>(&outE[(size_t)n * 64 + 4 * sl]) = we;
    }
}

// ---------------- output head (reads split x) ----------------

__global__ void k_out(const ushort* __restrict__ xh, const ushort* __restrict__ xe,
                      const float* __restrict__ Wout, const float* __restrict__ bout,
                      float* __restrict__ y) {
    int lane = threadIdx.x;
#pragma unroll
    for (int i = 0; i < 2; ++i) {
        float x0 = bf2f(xh[i * D + lane]) + bf2f(xe[i * D + lane]);
        float x1 = bf2f(xh[i * D + 64 + lane]) + bf2f(xe[i * D + 64 + lane]);
        float v = x0 * Wout[lane] + x1 * Wout[64 + lane];
        v += __shfl_xor(v, 1); v += __shfl_xor(v, 2); v += __shfl_xor(v, 4);
        v += __shfl_xor(v, 8); v += __shfl_xor(v, 16); v += __shfl_xor(v, 32);
        if (lane == 0) y[i] = v + bout[0];
    }
}

// ---------------- launch ----------------

extern "C" void kernel_launch(void* const* d_in, const int* in_sizes, int n_in,
                              void* d_out, int out_size, void* d_ws, size_t ws_size,
                              hipStream_t stream) {
    const float* x_in = (const float*)d_in[0];
    const int*   ei   = (const int*)d_in[1];
    const float* Wl   = (const float*)d_in[2];
    const float* bl   = (const float*)d_in[3];
    const float* Wr   = (const float*)d_in[4];
    const float* br   = (const float*)d_in[5];
    const float* att  = (const float*)d_in[6];
    const float* bias = (const float*)d_in[7];
    const float* Wout = (const float*)d_in[8];
    const float* bout = (const float*)d_in[9];
    float* y = (float*)d_out;

    char* ws = (char*)d_ws;
    size_t o = 0;
    auto alloc = [&](size_t bytes) -> void* {
        void* p = ws + o;
        o = (o + bytes + 255) & ~(size_t)255;
        return p;
    };
    ushort* XhA = (ushort*)alloc((size_t)NN * D * 2);
    ushort* XeA = (ushort*)alloc((size_t)NN * D * 2);
    ushort* XhB = (ushort*)alloc((size_t)NN * D * 2);
    ushort* XeB = (ushort*)alloc((size_t)NN * D * 2);
    ushort* xlh = (ushort*)alloc((size_t)NN * D * 2);
    ushort* xrh = (ushort*)alloc((size_t)NN * D * 2);
    ushort* Wth = (ushort*)alloc((size_t)NL * 256 * 128 * 2);
    ushort* Wtl = (ushort*)alloc((size_t)NL * 256 * 128 * 2);
    int* counts   = (int*)alloc((size_t)NN * 4);
    int* offsets  = (int*)alloc(((size_t)NN + 1) * 4);
    int* cursor   = (int*)alloc((size_t)NN * 4);
    int* srcs     = (int*)alloc((size_t)ET * 4);
    int* partials = (int*)alloc(256 * 4);
    (void)ws_size; (void)in_sizes; (void)n_in; (void)out_size;

    // CSR by dst with resolved srcs (layer-invariant) + deterministic segment
    // sort (wave bitonic) + W prep + X split
    hipMemsetAsync(counts, 0, (size_t)NN * 4, stream);
    k_hist<<<(ET + 255) / 256, 256, 0, stream>>>(ei, counts);
    k_scan1<<<NB_SCAN, 256, 0, stream>>>(counts, offsets, partials);
    k_scan2<<<1, 128, 0, stream>>>(partials, offsets);
    k_scan3<<<NB_SCAN, 256, 0, stream>>>(partials, offsets, cursor);
    k_scatter<<<(ET + 255) / 256, 256, 0, stream>>>(ei, cursor, srcs);
    k_sortseg<<<(NN + 3) / 4, 256, 0, stream>>>(offsets, srcs);
    k_wprep<<<NL * 8, 256, 0, stream>>>(Wl, Wr, Wth, Wtl);
    k_xsplit<<<NN * D / 1024, 256, 0, stream>>>(x_in, XhA, XeA);

    const int mgrid = (NN + 63) / 64;   // 469
    for (int i = 0; i < NL; ++i) {
        const ushort* inH = (i & 1) ? XhB : XhA;
        const ushort* inE = (i & 1) ? XeB : XeA;
        ushort* oH = (i & 1) ? XhA : XhB;
        ushort* oE = (i & 1) ? XeA : XeB;
        k_mm<<<dim3(mgrid, 4), 256, 0, stream>>>(inH, inE,
                                                 Wth + (size_t)i * 256 * 128,
                                                 Wtl + (size_t)i * 256 * 128,
                                                 bl + i * D, br + i * D, xlh, xrh);
        k_fused<<<NN / 4, 256, 0, stream>>>(offsets, srcs, (const uint32*)xlh,
                                            (const uint32*)xrh,
                                            att + i * NH * HD, bias + i * D,
                                            (uint32*)oH, (uint32*)oE);
    }
    k_out<<<1, 64, 0, stream>>>(XhB, XeB, Wout, bout, y);  // i=6 even -> out B
}